// Round 2
// baseline (233.012 us; speedup 1.0000x reference)
//
#include <hip/hip_runtime.h>

// One 8x8 block per thread, fully in registers. No LDS, no barriers.
// out[8R+i][8C+l] = 128 + sum_{j,k} M[j][i] * Q[j][k] * x[8R+j][8C+k]
//
// Lane n -> block col c = n&127 (consecutive lanes = consecutive 32B blocks,
// so each wave's loads/stores union to contiguous 2KB per image row).
// mtx/qt are wave-uniform with constant offsets -> scalar loads (SGPRs).
// Rows loaded in two halves of 4 to bound peak VGPR (~T[64] + 4 rows).

__global__ __launch_bounds__(256) void bidct_kernel(
    const float* __restrict__ x, const float* __restrict__ qt,
    const float* __restrict__ mtx, float* __restrict__ out)
{
    const int n   = blockIdx.x * 256 + threadIdx.x;
    const int img = n >> 14;           // 16384 blocks per 1024x1024 image
    const int m   = n & 16383;
    const int br  = m >> 7;            // block row 0..127
    const int bc  = m & 127;           // block col 0..127
    const size_t base = ((size_t)img << 20) + ((size_t)br << 13) + ((size_t)bc << 3);

    const float* __restrict__ px = x + base;

    // ---- Stage 1: T[i][k] = sum_j M[j][i] * (Q[j][k] * X[j][k]) ----
    float T[8][8];
#pragma unroll
    for (int i = 0; i < 8; ++i)
#pragma unroll
        for (int k = 0; k < 8; ++k)
            T[i][k] = 0.0f;

#pragma unroll
    for (int jh = 0; jh < 2; ++jh) {
        float4 xa[4], xb[4];
#pragma unroll
        for (int jj = 0; jj < 4; ++jj) {
            const float* row = px + (size_t)(jh * 4 + jj) * 1024;
            xa[jj] = *reinterpret_cast<const float4*>(row);
            xb[jj] = *reinterpret_cast<const float4*>(row + 4);
        }
#pragma unroll
        for (int jj = 0; jj < 4; ++jj) {
            const int j = jh * 4 + jj;
            float xq[8];
            xq[0] = xa[jj].x * qt[j * 8 + 0];
            xq[1] = xa[jj].y * qt[j * 8 + 1];
            xq[2] = xa[jj].z * qt[j * 8 + 2];
            xq[3] = xa[jj].w * qt[j * 8 + 3];
            xq[4] = xb[jj].x * qt[j * 8 + 4];
            xq[5] = xb[jj].y * qt[j * 8 + 5];
            xq[6] = xb[jj].z * qt[j * 8 + 6];
            xq[7] = xb[jj].w * qt[j * 8 + 7];
#pragma unroll
            for (int i = 0; i < 8; ++i) {
                const float mji = mtx[j * 8 + i];
#pragma unroll
                for (int k = 0; k < 8; ++k)
                    T[i][k] = fmaf(mji, xq[k], T[i][k]);
            }
        }
    }

    // ---- Stage 2: o[i][l] = 128 + sum_k T[i][k] * M[k][l]; store row i ----
    float* __restrict__ po = out + base;
#pragma unroll
    for (int i = 0; i < 8; ++i) {
        float o[8] = {128.f, 128.f, 128.f, 128.f, 128.f, 128.f, 128.f, 128.f};
#pragma unroll
        for (int k = 0; k < 8; ++k) {
            const float tk = T[i][k];
#pragma unroll
            for (int l = 0; l < 8; ++l)
                o[l] = fmaf(tk, mtx[k * 8 + l], o[l]);
        }
        float* row = po + (size_t)i * 1024;
        *reinterpret_cast<float4*>(row)     = make_float4(o[0], o[1], o[2], o[3]);
        *reinterpret_cast<float4*>(row + 4) = make_float4(o[4], o[5], o[6], o[7]);
    }
}

extern "C" void kernel_launch(void* const* d_in, const int* in_sizes, int n_in,
                              void* d_out, int out_size, void* d_ws, size_t ws_size,
                              hipStream_t stream) {
    const float* x   = (const float*)d_in[0];
    const float* qt  = (const float*)d_in[1];
    const float* mtx = (const float*)d_in[2];
    float*       out = (float*)d_out;

    const int total_blocks = out_size / 64;   // out_size is in floats; 64 per 8x8 block
    const int grid         = total_blocks / 256;  // 2048 workgroups of 256 threads
    bidct_kernel<<<grid, 256, 0, stream>>>(x, qt, mtx, out);
}